// Round 1
// baseline (552.013 us; speedup 1.0000x reference)
//
#include <hip/hip_runtime.h>

static constexpr int B = 8, N = 1024, C = 48, H = 8, HD = 6, NT = B * N; // 8192 tokens
static constexpr int QKVO = 3 * C;   // 144
static constexpr int HID = 24, KB = 8;
static constexpr int C1 = 128;

#define DEVFN __device__ __forceinline__

DEVFN float wsum(float v) {
#pragma unroll
  for (int m = 32; m; m >>= 1) v += __shfl_xor(v, m, 64);
  return v;
}
DEVFN float wmax(float v) {
#pragma unroll
  for (int m = 32; m; m >>= 1) v = fmaxf(v, __shfl_xor(v, m, 64));
  return v;
}
DEVFN float gsum16(float v) {
#pragma unroll
  for (int m = 8; m; m >>= 1) v += __shfl_xor(v, m, 16);
  return v;
}
DEVFN float gmax16(float v) {
#pragma unroll
  for (int m = 8; m; m >>= 1) v = fmaxf(v, __shfl_xor(v, m, 16));
  return v;
}

// Cubic B-spline bases, GRID_SIZE=5, order=3, grid_range [-1,1] -> knots -2.2 + 0.4*j, j=0..11.
// Exact replication of the reference recurrence (zero outside [-2.2, 2.2)).
DEVFN void bspline8(float x, float* bs) {
  float b[11];
#pragma unroll
  for (int j = 0; j < 11; ++j) {
    float gj = -2.2f + 0.4f * j;
    float gj1 = -2.2f + 0.4f * (j + 1);
    b[j] = (x >= gj && x < gj1) ? 1.0f : 0.0f;
  }
#pragma unroll
  for (int j = 0; j < 10; ++j) {           // k=1, denom 0.4
    float gj = -2.2f + 0.4f * j;
    b[j] = (x - gj) * 2.5f * b[j] + ((gj + 0.8f) - x) * 2.5f * b[j + 1];
  }
#pragma unroll
  for (int j = 0; j < 9; ++j) {            // k=2, denom 0.8
    float gj = -2.2f + 0.4f * j;
    b[j] = (x - gj) * 1.25f * b[j] + ((gj + 1.2f) - x) * 1.25f * b[j + 1];
  }
#pragma unroll
  for (int j = 0; j < 8; ++j) {            // k=3, denom 1.2
    float gj = -2.2f + 0.4f * j;
    bs[j] = (x - gj) * (1.0f / 1.2f) * b[j] + ((gj + 1.6f) - x) * (1.0f / 1.2f) * b[j + 1];
  }
}

// ---------------- kernel 1: LN1 + QKV projection -------------------------
__global__ __launch_bounds__(256) void k_ln_qkv(
    const float* __restrict__ x, const float* __restrict__ g1, const float* __restrict__ b1,
    const float* __restrict__ wqkv, float* __restrict__ q, float* __restrict__ k,
    float* __restrict__ v) {
  __shared__ float wl[QKVO * 49];   // [o][i], stride 49 (odd -> conflict-free)
  __shared__ float nb[4][C];
  int tid = threadIdx.x;
  for (int e = tid; e < QKVO * C; e += 256) wl[(e / C) * 49 + (e % C)] = wqkv[e];
  int wave = tid >> 6, lane = tid & 63;
  int tok = blockIdx.x * 4 + wave;
  const float* xr = x + tok * C;
  float xv = (lane < C) ? xr[lane] : 0.f;
  float s = wsum(xv), s2 = wsum(xv * xv);
  float mean = s * (1.f / C);
  float var = s2 * (1.f / C) - mean * mean;
  float rstd = rsqrtf(var + 1e-5f);
  if (lane < C) nb[wave][lane] = (xv - mean) * rstd * g1[lane] + b1[lane];
  __syncthreads();
  int b = tok >> 10, n = tok & 1023;
#pragma unroll
  for (int r = 0; r < 3; ++r) {
    int o = lane + (r << 6);
    if (o < QKVO) {
      float acc = 0.f;
#pragma unroll
      for (int i = 0; i < C; ++i) acc += nb[wave][i] * wl[o * 49 + i];
      int ssel = o / C;
      int rem = o - ssel * C;
      int hh = rem / HD;
      int d = rem - hh * HD;
      float* dst = ssel == 0 ? q : (ssel == 1 ? k : v);
      dst[((b * H + hh) * N + n) * HD + d] = acc;
    }
  }
}

// ---------------- kernel 2: global attention (+ attn probs out) ----------
__global__ __launch_bounds__(256) void k_gattn(
    const float* __restrict__ q, const float* __restrict__ k, const float* __restrict__ v,
    float* __restrict__ attn, float* __restrict__ xg) {
  __shared__ float2 kt[3][N];   // [d-pair][kpos]
  __shared__ float2 vt[3][N];
  int tid = threadIdx.x;
  int bh = blockIdx.x >> 5;
  int rb = blockIdx.x & 31;
  const float* kg = k + bh * N * HD;
  const float* vg = v + bh * N * HD;
  float* ktf = (float*)kt;
  float* vtf = (float*)vt;
  for (int e = tid; e < N * HD; e += 256) {
    int kp = e / 6, d = e - kp * 6;
    int a = (d >> 1) * 2048 + (kp << 1) + (d & 1);
    ktf[a] = kg[e];
    vtf[a] = vg[e];
  }
  __syncthreads();
  int wave = tid >> 6, lane = tid & 63;
  const float scl = 0.40824829046386301637f;  // 6^-0.5
  int b = bh >> 3, hh = bh & 7;
#pragma unroll 1
  for (int rr = 0; rr < 8; ++rr) {
    int qrow = (rb << 5) + (wave << 3) + rr;
    const float2* qp = (const float2*)(q + (bh * N + qrow) * HD);
    float2 q0 = qp[0], q1 = qp[1], q2 = qp[2];
    float sv[16];
    float mx = -1e30f;
#pragma unroll
    for (int it = 0; it < 16; ++it) {
      int kp = lane + (it << 6);
      float2 a0 = kt[0][kp], a1 = kt[1][kp], a2 = kt[2][kp];
      float dp = q0.x * a0.x + q0.y * a0.y + q1.x * a1.x + q1.y * a1.y + q2.x * a2.x + q2.y * a2.y;
      sv[it] = dp * scl;
      mx = fmaxf(mx, sv[it]);
    }
    mx = wmax(mx);
    float sum = 0.f;
#pragma unroll
    for (int it = 0; it < 16; ++it) {
      sv[it] = __expf(sv[it] - mx);
      sum += sv[it];
    }
    sum = wsum(sum);
    float inv = 1.f / sum;
    float a0 = 0, a1 = 0, a2 = 0, a3 = 0, a4 = 0, a5 = 0;
    float* arow = attn + (size_t)(bh * N + qrow) * N;
#pragma unroll
    for (int it = 0; it < 16; ++it) {
      int kp = lane + (it << 6);
      float p = sv[it];
      arow[kp] = p * inv;
      float2 v0 = vt[0][kp], v1 = vt[1][kp], v2 = vt[2][kp];
      a0 += p * v0.x; a1 += p * v0.y; a2 += p * v1.x;
      a3 += p * v1.y; a4 += p * v2.x; a5 += p * v2.y;
    }
    a0 = wsum(a0) * inv; a1 = wsum(a1) * inv; a2 = wsum(a2) * inv;
    a3 = wsum(a3) * inv; a4 = wsum(a4) * inv; a5 = wsum(a5) * inv;
    if (lane == 0) {
      float* o = xg + (b * N + qrow) * C + hh * HD;
      o[0] = a0; o[1] = a1; o[2] = a2; o[3] = a3; o[4] = a4; o[5] = a5;
    }
  }
}

// ---------------- kernel 3: local window attention -----------------------
__global__ __launch_bounds__(256) void k_lattn(
    const float* __restrict__ q, const float* __restrict__ k, const float* __restrict__ v,
    float* __restrict__ xl) {
  int tid = threadIdx.x;
  int wave = tid >> 6, lane = tid & 63;
  int win = blockIdx.x * 4 + wave;  // 4096 windows
  int bh = win >> 6;
  int wloc = win & 63;
  int n0 = wloc << 4;
  int b = bh >> 3, hh = bh & 7;
  int kk = lane & 15, g = lane >> 4;
  const float* kb = k + (bh * N + n0) * HD;
  const float* vb = v + (bh * N + n0) * HD;
  float kv[6], vv[6];
#pragma unroll
  for (int d = 0; d < 6; ++d) {
    kv[d] = kb[kk * 6 + d];
    vv[d] = vb[kk * 6 + d];
  }
  const float scl = 0.40824829046386301637f;
#pragma unroll
  for (int pass = 0; pass < 4; ++pass) {
    int qr = (pass << 2) + g;
    const float* qp = q + (bh * N + n0 + qr) * HD;
    float s = 0.f;
#pragma unroll
    for (int d = 0; d < 6; ++d) s += qp[d] * kv[d];
    s *= scl;
    float mx = gmax16(s);
    float p = __expf(s - mx);
    float sum = gsum16(p);
    float inv = 1.f / sum;
    float o[6];
#pragma unroll
    for (int d = 0; d < 6; ++d) o[d] = gsum16(p * vv[d]) * inv;
    if (kk == 0) {
      float* dst = xl + (size_t)(b * N + n0 + qr) * C + hh * HD;
#pragma unroll
      for (int d = 0; d < 6; ++d) dst[d] = o[d];
    }
  }
}

// ---------------- kernel 4: proj + residual + LN2 ------------------------
__global__ __launch_bounds__(256) void k_proj(
    const float* __restrict__ x, const float* __restrict__ xg, const float* __restrict__ xl,
    const float* __restrict__ wp, const float* __restrict__ bp,
    const float* __restrict__ g2, const float* __restrict__ b2,
    float* __restrict__ x1, float* __restrict__ n2) {
  __shared__ float wl[C * 49];
  __shared__ float ab[4][C];
  int tid = threadIdx.x;
  for (int e = tid; e < C * C; e += 256) wl[(e / C) * 49 + (e % C)] = wp[e];
  int wave = tid >> 6, lane = tid & 63;
  int tok = blockIdx.x * 4 + wave;
  if (lane < C) ab[wave][lane] = xg[tok * C + lane] + xl[tok * C + lane];
  __syncthreads();
  float x1v = 0.f;
  if (lane < C) {
    float acc = bp[lane];
#pragma unroll
    for (int i = 0; i < C; ++i) acc += ab[wave][i] * wl[lane * 49 + i];
    x1v = x[tok * C + lane] + acc;
  }
  float s = wsum(lane < C ? x1v : 0.f);
  float s2 = wsum(lane < C ? x1v * x1v : 0.f);
  float mean = s * (1.f / C), var = s2 * (1.f / C) - mean * mean;
  float rstd = rsqrtf(var + 1e-5f);
  if (lane < C) {
    x1[tok * C + lane] = x1v;
    n2[tok * C + lane] = (x1v - mean) * rstd * g2[lane] + b2[lane];
  }
}

// ---------------- kernel 5: KAN layer 1 (48 -> 24) -----------------------
__global__ __launch_bounds__(256) void k_kan1(
    const float* __restrict__ n2, const float* __restrict__ bw1,
    const float* __restrict__ sw1, const float* __restrict__ ss1,
    float* __restrict__ kanh) {
  __shared__ float swt[C * KB * HID];  // [i*8+k][o]
  __shared__ float bwt[C * HID];       // [i][o]
  __shared__ float sst[C * HID];
  __shared__ float bas[4][C][KB];
  __shared__ float sil[4][C];
  int tid = threadIdx.x;
  for (int e = tid; e < C * KB * HID; e += 256) {
    int o = e / (C * KB);
    int rem = e - o * (C * KB);
    swt[rem * HID + o] = sw1[e];
  }
  for (int e = tid; e < C * HID; e += 256) {
    int o = e / C, i = e - o * C;
    bwt[i * HID + o] = bw1[e];
    sst[i * HID + o] = ss1[e];
  }
  int wave = tid >> 6, lane = tid & 63;
  int tok = blockIdx.x * 4 + wave;
  if (lane < C) {
    float xv = n2[tok * C + lane];
    sil[wave][lane] = xv / (1.f + __expf(-xv));
    float bs[KB];
    bspline8(xv, bs);
#pragma unroll
    for (int kk = 0; kk < KB; ++kk) bas[wave][lane][kk] = bs[kk];
  }
  __syncthreads();
  int o = lane & 31;
  int hf = lane >> 5;
  float acc = 0.f;
  if (o < HID) {
    int i0 = hf * 24;
#pragma unroll
    for (int ii = 0; ii < 24; ++ii) {
      int i = i0 + ii;
      float sp = 0.f;
#pragma unroll
      for (int kk = 0; kk < KB; ++kk) sp += bas[wave][i][kk] * swt[(i * KB + kk) * HID + o];
      acc += sil[wave][i] * bwt[i * HID + o] + sst[i * HID + o] * sp;
    }
  }
  acc += __shfl_xor(acc, 32, 64);
  if (lane < HID) kanh[tok * HID + lane] = acc;
}

// ---------------- kernel 6: KAN layer 2 (24 -> 48) + residual ------------
__global__ __launch_bounds__(256) void k_kan2(
    const float* __restrict__ kanh, const float* __restrict__ x1,
    const float* __restrict__ bw2, const float* __restrict__ sw2,
    const float* __restrict__ ss2, float* __restrict__ x2) {
  __shared__ float swt[HID * KB * C];  // [i*8+k][o]
  __shared__ float bwt[HID * C];
  __shared__ float sst[HID * C];
  __shared__ float bas[4][HID][KB];
  __shared__ float sil[4][HID];
  int tid = threadIdx.x;
  for (int e = tid; e < HID * KB * C; e += 256) {
    int o = e / (HID * KB);
    int rem = e - o * (HID * KB);
    swt[rem * C + o] = sw2[e];
  }
  for (int e = tid; e < HID * C; e += 256) {
    int o = e / HID, i = e - o * HID;
    bwt[i * C + o] = bw2[e];
    sst[i * C + o] = ss2[e];
  }
  int wave = tid >> 6, lane = tid & 63;
  int tok = blockIdx.x * 4 + wave;
  if (lane < HID) {
    float xv = kanh[tok * HID + lane];
    sil[wave][lane] = xv / (1.f + __expf(-xv));
    float bs[KB];
    bspline8(xv, bs);
#pragma unroll
    for (int kk = 0; kk < KB; ++kk) bas[wave][lane][kk] = bs[kk];
  }
  __syncthreads();
  if (lane < C) {
    float acc = 0.f;
#pragma unroll
    for (int i = 0; i < HID; ++i) {
      float sp = 0.f;
#pragma unroll
      for (int kk = 0; kk < KB; ++kk) sp += bas[wave][i][kk] * swt[(i * KB + kk) * C + lane];
      acc += sil[wave][i] * bwt[i * C + lane] + sst[i * C + lane] * sp;
    }
    x2[tok * C + lane] = x1[tok * C + lane] + acc;
  }
}

// ---------------- kernel 7: conv1 (48 -> 128, k=3) -----------------------
__global__ __launch_bounds__(256) void k_conv1(
    const float* __restrict__ x, const float* __restrict__ w1, const float* __restrict__ bc1,
    float* __restrict__ h1) {
  __shared__ float wt[72 * C1];  // [i3][o] for one i-half
  __shared__ float xr[18 * C];
  int tid = threadIdx.x;
  int b = blockIdx.x >> 6;
  int t0 = (blockIdx.x & 63) << 4;
  for (int e = tid; e < 18 * C; e += 256) {
    int r = e / C, c = e - r * C;
    int n = t0 - 1 + r;
    xr[e] = (n >= 0 && n < N) ? x[(b * N + n) * C + c] : 0.f;
  }
  int wave = tid >> 6, lane = tid & 63;
  float acc0[4] = {0, 0, 0, 0}, acc1[4] = {0, 0, 0, 0};
  for (int hf = 0; hf < 2; ++hf) {
    __syncthreads();
    for (int e = tid; e < 72 * C1; e += 256) {
      int i3 = e / C1, o = e - i3 * C1;
      int ii = i3 / 3, dk = i3 - ii * 3;
      wt[e] = w1[(o * C + hf * 24 + ii) * 3 + dk];
    }
    __syncthreads();
#pragma unroll
    for (int tt = 0; tt < 4; ++tt) {
      int t = (wave << 2) + tt;
      float a0 = acc0[tt], a1 = acc1[tt];
#pragma unroll 8
      for (int ii = 0; ii < 24; ++ii) {
#pragma unroll
        for (int dk = 0; dk < 3; ++dk) {
          float xin = xr[(t + dk) * C + hf * 24 + ii];
          a0 += xin * wt[(ii * 3 + dk) * C1 + lane];
          a1 += xin * wt[(ii * 3 + dk) * C1 + 64 + lane];
        }
      }
      acc0[tt] = a0;
      acc1[tt] = a1;
    }
  }
  float bb0 = bc1[lane], bb1 = bc1[64 + lane];
#pragma unroll
  for (int tt = 0; tt < 4; ++tt) {
    int n = t0 + (wave << 2) + tt;
    h1[(b * N + n) * C1 + lane] = acc0[tt] + bb0;
    h1[(b * N + n) * C1 + 64 + lane] = acc1[tt] + bb1;
  }
}

// ---------------- kernel 8: conv2 + LN(g1,b1) + sc*h + x2 -> out ---------
__global__ __launch_bounds__(256) void k_conv2out(
    const float* __restrict__ h1, const float* __restrict__ w3, const float* __restrict__ bc3,
    const float* __restrict__ g1, const float* __restrict__ b1,
    const float* __restrict__ x2, const float* __restrict__ scp,
    float* __restrict__ out) {
  __shared__ float wt[192 * C];  // [i3][c] for one i-half
  __shared__ float hr[18 * C1];
  int tid = threadIdx.x;
  int b = blockIdx.x >> 6;
  int t0 = (blockIdx.x & 63) << 4;
  for (int e = tid; e < 18 * C1; e += 256) {
    int r = e / C1, c = e - r * C1;
    int n = t0 - 1 + r;
    hr[e] = (n >= 0 && n < N) ? h1[(b * N + n) * C1 + c] : 0.f;
  }
  int wave = tid >> 6, lane = tid & 63;
  float acc[4] = {0, 0, 0, 0};
  for (int hf = 0; hf < 2; ++hf) {
    __syncthreads();
    for (int e = tid; e < 192 * C; e += 256) {
      int i3 = e / C, c = e - i3 * C;
      int ii = i3 / 3, dk = i3 - ii * 3;
      wt[e] = w3[(c * C1 + hf * 64 + ii) * 3 + dk];
    }
    __syncthreads();
    if (lane < C) {
#pragma unroll
      for (int tt = 0; tt < 4; ++tt) {
        int t = (wave << 2) + tt;
        float a = acc[tt];
#pragma unroll 8
        for (int ii = 0; ii < 64; ++ii) {
#pragma unroll
          for (int dk = 0; dk < 3; ++dk) {
            a += hr[(t + dk) * C1 + hf * 64 + ii] * wt[(ii * 3 + dk) * C + lane];
          }
        }
        acc[tt] = a;
      }
    }
  }
  float sc0 = scp[0];
#pragma unroll
  for (int tt = 0; tt < 4; ++tt) {
    int n = t0 + (wave << 2) + tt;
    float val = (lane < C) ? acc[tt] + bc3[lane] : 0.f;
    float s = wsum(val), s2 = wsum(val * val);
    float mean = s * (1.f / C), var = s2 * (1.f / C) - mean * mean;
    float rstd = rsqrtf(var + 1e-5f);
    if (lane < C) {
      float hn = (val - mean) * rstd * g1[lane] + b1[lane];
      out[(b * N + n) * C + lane] = sc0 * hn + x2[(b * N + n) * C + lane];
    }
  }
}

extern "C" void kernel_launch(void* const* d_in, const int* in_sizes, int n_in,
                              void* d_out, int out_size, void* d_ws, size_t ws_size,
                              hipStream_t stream) {
  (void)in_sizes; (void)n_in; (void)out_size; (void)ws_size;
  const float* x    = (const float*)d_in[0];
  const float* g1   = (const float*)d_in[1];
  const float* b1   = (const float*)d_in[2];
  const float* wqkv = (const float*)d_in[3];
  const float* wp   = (const float*)d_in[4];
  const float* bp   = (const float*)d_in[5];
  const float* g2   = (const float*)d_in[6];
  const float* b2   = (const float*)d_in[7];
  const float* bw1  = (const float*)d_in[8];
  const float* sw1  = (const float*)d_in[9];
  const float* ss1  = (const float*)d_in[10];
  const float* bw2  = (const float*)d_in[11];
  const float* sw2  = (const float*)d_in[12];
  const float* ss2  = (const float*)d_in[13];
  const float* w1   = (const float*)d_in[14];
  const float* bc1  = (const float*)d_in[15];
  const float* w3   = (const float*)d_in[16];
  const float* bc3  = (const float*)d_in[17];
  const float* scp  = (const float*)d_in[18];

  float* out  = (float*)d_out;
  float* attn = out + (size_t)NT * C;  // out first, then attn_global

  float* ws   = (float*)d_ws;
  float* q    = ws;                 // 393216
  float* k    = ws + 393216;        // 393216
  float* v    = ws + 786432;        // 393216
  float* xg   = ws + 1179648;       // 393216
  float* xl   = ws + 1572864;       // 393216
  float* x1   = ws + 1966080;       // 393216
  float* n2   = ws + 2359296;       // 393216
  float* kanh = ws + 2752512;       // 196608
  float* x2   = ws;                 // reuse q (dead after local attn)
  float* h1   = ws + 393216;        // reuse k,v,xg (dead after proj)

  k_ln_qkv<<<NT / 4, 256, 0, stream>>>(x, g1, b1, wqkv, q, k, v);
  k_gattn<<<B * H * 32, 256, 0, stream>>>(q, k, v, attn, xg);
  k_lattn<<<B * H * 64 / 4, 256, 0, stream>>>(q, k, v, xl);
  k_proj<<<NT / 4, 256, 0, stream>>>(x, xg, xl, wp, bp, g2, b2, x1, n2);
  k_kan1<<<NT / 4, 256, 0, stream>>>(n2, bw1, sw1, ss1, kanh);
  k_kan2<<<NT / 4, 256, 0, stream>>>(kanh, x1, bw2, sw2, ss2, x2);
  k_conv1<<<512, 256, 0, stream>>>(x, w1, bc1, h1);
  k_conv2out<<<512, 256, 0, stream>>>(h1, w3, bc3, g1, b1, x2, scp, out);
}

// Round 2
// 504.029 us; speedup vs baseline: 1.0952x; 1.0952x over previous
//
#include <hip/hip_runtime.h>

static constexpr int B = 8, N = 1024, C = 48, H = 8, HD = 6, NT = B * N; // 8192 tokens
static constexpr int QKVO = 3 * C;   // 144
static constexpr int HID = 24, KB = 8;
static constexpr int C1 = 128;

#define DEVFN __device__ __forceinline__

DEVFN float wsum(float v) {
#pragma unroll
  for (int m = 32; m; m >>= 1) v += __shfl_xor(v, m, 64);
  return v;
}
DEVFN float wmax(float v) {
#pragma unroll
  for (int m = 32; m; m >>= 1) v = fmaxf(v, __shfl_xor(v, m, 64));
  return v;
}
DEVFN float gsum16(float v) {
#pragma unroll
  for (int m = 8; m; m >>= 1) v += __shfl_xor(v, m, 16);
  return v;
}
DEVFN float gmax16(float v) {
#pragma unroll
  for (int m = 8; m; m >>= 1) v = fmaxf(v, __shfl_xor(v, m, 16));
  return v;
}

// Cubic B-spline bases, GRID_SIZE=5, order=3, knots -2.2 + 0.4*j, j=0..11.
DEVFN void bspline8(float x, float* bs) {
  float b[11];
#pragma unroll
  for (int j = 0; j < 11; ++j) {
    float gj = -2.2f + 0.4f * j;
    float gj1 = -2.2f + 0.4f * (j + 1);
    b[j] = (x >= gj && x < gj1) ? 1.0f : 0.0f;
  }
#pragma unroll
  for (int j = 0; j < 10; ++j) {
    float gj = -2.2f + 0.4f * j;
    b[j] = (x - gj) * 2.5f * b[j] + ((gj + 0.8f) - x) * 2.5f * b[j + 1];
  }
#pragma unroll
  for (int j = 0; j < 9; ++j) {
    float gj = -2.2f + 0.4f * j;
    b[j] = (x - gj) * 1.25f * b[j] + ((gj + 1.2f) - x) * 1.25f * b[j + 1];
  }
#pragma unroll
  for (int j = 0; j < 8; ++j) {
    float gj = -2.2f + 0.4f * j;
    bs[j] = (x - gj) * (1.0f / 1.2f) * b[j] + ((gj + 1.6f) - x) * (1.0f / 1.2f) * b[j + 1];
  }
}

// ---------------- kernel 1: LN1 + QKV projection -------------------------
__global__ __launch_bounds__(256) void k_ln_qkv(
    const float* __restrict__ x, const float* __restrict__ g1, const float* __restrict__ b1,
    const float* __restrict__ wqkv, float* __restrict__ q, float* __restrict__ k,
    float* __restrict__ v) {
  __shared__ float wl[QKVO * 49];   // [o][i], stride 49 -> conflict-free
  __shared__ float nb[4][C];
  int tid = threadIdx.x;
  for (int e = tid; e < QKVO * C; e += 256) wl[(e / C) * 49 + (e % C)] = wqkv[e];
  int wave = tid >> 6, lane = tid & 63;
  int tok = blockIdx.x * 4 + wave;
  const float* xr = x + tok * C;
  float xv = (lane < C) ? xr[lane] : 0.f;
  float s = wsum(xv), s2 = wsum(xv * xv);
  float mean = s * (1.f / C);
  float var = s2 * (1.f / C) - mean * mean;
  float rstd = rsqrtf(var + 1e-5f);
  if (lane < C) nb[wave][lane] = (xv - mean) * rstd * g1[lane] + b1[lane];
  __syncthreads();
  int b = tok >> 10, n = tok & 1023;
#pragma unroll
  for (int r = 0; r < 3; ++r) {
    int o = lane + (r << 6);
    if (o < QKVO) {
      float acc = 0.f;
#pragma unroll
      for (int i = 0; i < C; ++i) acc += nb[wave][i] * wl[o * 49 + i];
      int ssel = o / C;
      int rem = o - ssel * C;
      int hh = rem / HD;
      int d = rem - hh * HD;
      float* dst = ssel == 0 ? q : (ssel == 1 ? k : v);
      dst[((b * H + hh) * N + n) * HD + d] = acc;
    }
  }
}

// ------- kernel 2: global attention + probs + local attention ------------
__global__ __launch_bounds__(256) void k_gattn(
    const float* __restrict__ q, const float* __restrict__ k, const float* __restrict__ v,
    float* __restrict__ attn, float* __restrict__ xgl) {
  __shared__ float2 kt[3][N];   // [d-pair][kpos]
  __shared__ float2 vt[3][N];
  __shared__ float ob[64][6];   // per-row global-attn output
  int tid = threadIdx.x;
  int bh = blockIdx.x >> 4;     // 1024 blocks: 64 rows each
  int rb = blockIdx.x & 15;
  const float* kg = k + bh * N * HD;
  const float* vg = v + bh * N * HD;
  float* ktf = (float*)kt;
  float* vtf = (float*)vt;
  for (int e = tid; e < N * HD; e += 256) {
    int kp = e / 6, d = e - kp * 6;
    int a = (d >> 1) * 2048 + (kp << 1) + (d & 1);
    ktf[a] = kg[e];
    vtf[a] = vg[e];
  }
  __syncthreads();
  int wave = tid >> 6, lane = tid & 63;
  const float scl = 0.40824829046386301637f;  // 6^-0.5
  int b = bh >> 3, hh = bh & 7;
  int r0 = rb * 64 + wave * 16;
  // ---- phase 1: global attention, 16 rows per wave ----
#pragma unroll 2
  for (int rr = 0; rr < 16; ++rr) {
    int qrow = r0 + rr;
    const float2* qp = (const float2*)(q + (bh * N + qrow) * HD);
    float2 q0 = qp[0], q1 = qp[1], q2 = qp[2];
    float sv[16];
    float mx = -1e30f;
#pragma unroll
    for (int it = 0; it < 16; ++it) {
      int kp = lane + (it << 6);
      float2 a0 = kt[0][kp], a1 = kt[1][kp], a2 = kt[2][kp];
      float dp = q0.x * a0.x + q0.y * a0.y + q1.x * a1.x + q1.y * a1.y + q2.x * a2.x + q2.y * a2.y;
      sv[it] = dp * scl;
      mx = fmaxf(mx, sv[it]);
    }
    mx = wmax(mx);
    float sum = 0.f;
#pragma unroll
    for (int it = 0; it < 16; ++it) {
      sv[it] = __expf(sv[it] - mx);
      sum += sv[it];
    }
    sum = wsum(sum);
    float inv = 1.f / sum;
    float a0 = 0, a1 = 0, a2 = 0, a3 = 0, a4 = 0, a5 = 0;
    float* arow = attn + (size_t)(bh * N + qrow) * N;
#pragma unroll
    for (int it = 0; it < 16; ++it) {
      int kp = lane + (it << 6);
      float p = sv[it];
      __builtin_nontemporal_store(p * inv, arow + kp);
      float2 v0 = vt[0][kp], v1 = vt[1][kp], v2 = vt[2][kp];
      a0 += p * v0.x; a1 += p * v0.y; a2 += p * v1.x;
      a3 += p * v1.y; a4 += p * v2.x; a5 += p * v2.y;
    }
    a0 = wsum(a0) * inv; a1 = wsum(a1) * inv; a2 = wsum(a2) * inv;
    a3 = wsum(a3) * inv; a4 = wsum(a4) * inv; a5 = wsum(a5) * inv;
    if (lane == 0) {
      int li = wave * 16 + rr;
      ob[li][0] = a0; ob[li][1] = a1; ob[li][2] = a2;
      ob[li][3] = a3; ob[li][4] = a4; ob[li][5] = a5;
    }
  }
  // ---- phase 2: local window attention; wave's 16 rows == one window ----
  // (same wave wrote ob for these rows; LDS is wave-coherent, no barrier)
  int n0 = r0;                  // window base
  int kk = lane & 15, g = lane >> 4;
  float kv[6], vv[6];
#pragma unroll
  for (int d = 0; d < 6; ++d) {
    int a = (d >> 1) * 2048 + ((n0 + kk) << 1) + (d & 1);
    kv[d] = ktf[a];
    vv[d] = vtf[a];
  }
#pragma unroll
  for (int pass = 0; pass < 4; ++pass) {
    int qr = n0 + pass * 4 + g;
    const float* qp = q + (bh * N + qr) * HD;
    float s = 0.f;
#pragma unroll
    for (int d = 0; d < 6; ++d) s += qp[d] * kv[d];
    s *= scl;
    float mx = gmax16(s);
    float p = __expf(s - mx);
    float sum = gsum16(p);
    float inv = 1.f / sum;
    float o[6];
#pragma unroll
    for (int d = 0; d < 6; ++d) o[d] = gsum16(p * vv[d]) * inv;
    if (kk == 0) {
      int li = wave * 16 + pass * 4 + g;
      float* dst = xgl + (size_t)(b * N + qr) * C + hh * HD;
#pragma unroll
      for (int d = 0; d < 6; ++d) dst[d] = ob[li][d] + o[d];
    }
  }
}

// ------- kernel 3: proj + residual + LN2 + KAN1 + KAN2 + residual --------
__global__ __launch_bounds__(512) void k_mlp(
    const float* __restrict__ x, const float* __restrict__ xgl,
    const float* __restrict__ wp, const float* __restrict__ bp,
    const float* __restrict__ g2, const float* __restrict__ b2,
    const float* __restrict__ bw1, const float* __restrict__ sw1, const float* __restrict__ ss1,
    const float* __restrict__ bw2, const float* __restrict__ sw2, const float* __restrict__ ss2,
    float* __restrict__ x2) {
  __shared__ float wpl[C * 49];          // [o][i]
  __shared__ float bw1t[C * 25];         // [i][o], o<24
  __shared__ float ss1t[C * 25];
  __shared__ float sw1t[C * KB * 25];    // [i*8+k][o]
  __shared__ float bw2t[HID * 49];       // [i][o], o<48
  __shared__ float ss2t[HID * 49];
  __shared__ float sw2t[HID * KB * 49];  // [i*8+k][o]
  __shared__ float abuf[8][2][C];
  __shared__ float sil1[8][2][C];
  __shared__ float bas1[8][2][C][KB];
  __shared__ float sil2[8][2][HID];
  __shared__ float bas2[8][2][HID][KB];
  int tid = threadIdx.x;
  for (int e = tid; e < C * C; e += 512) wpl[(e / C) * 49 + (e % C)] = wp[e];
  for (int e = tid; e < HID * C; e += 512) {
    int o = e / C, i = e - o * C;
    bw1t[i * 25 + o] = bw1[e];
    ss1t[i * 25 + o] = ss1[e];
  }
  for (int e = tid; e < HID * C * KB; e += 512) {
    int o = e / (C * KB), r = e - o * (C * KB);
    sw1t[r * 25 + o] = sw1[e];
  }
  for (int e = tid; e < C * HID; e += 512) {
    int o = e / HID, i = e - o * HID;
    bw2t[i * 49 + o] = bw2[e];
    ss2t[i * 49 + o] = ss2[e];
  }
  for (int e = tid; e < C * HID * KB; e += 512) {
    int o = e / (HID * KB), r = e - o * (HID * KB);
    sw2t[r * 49 + o] = sw2[e];
  }
  __syncthreads();
  int wave = tid >> 6, lane = tid & 63;
  int tok0 = blockIdx.x * 16 + wave * 2;
  float x1v[2];
  // ---- phase A: proj + residual + LN2 + bases (per token) ----
#pragma unroll
  for (int tt = 0; tt < 2; ++tt) {
    int tok = tok0 + tt;
    float acc = 0.f, xin = 0.f;
    if (lane < C) {
      abuf[wave][tt][lane] = xgl[tok * C + lane];
      xin = x[tok * C + lane];
    }
    if (lane < C) {
      acc = bp[lane];
#pragma unroll
      for (int i = 0; i < C; ++i) acc += abuf[wave][tt][i] * wpl[lane * 49 + i];
    }
    float xv = (lane < C) ? xin + acc : 0.f;
    x1v[tt] = xv;
    float s = wsum(xv), s2 = wsum(xv * xv);
    float mean = s * (1.f / C), var = s2 * (1.f / C) - mean * mean;
    float rstd = rsqrtf(var + 1e-5f);
    if (lane < C) {
      float n2v = (xv - mean) * rstd * g2[lane] + b2[lane];
      sil1[wave][tt][lane] = n2v / (1.f + __expf(-n2v));
      float bs[KB];
      bspline8(n2v, bs);
#pragma unroll
      for (int kk = 0; kk < KB; ++kk) bas1[wave][tt][lane][kk] = bs[kk];
    }
  }
  // ---- phase B: KAN1 (48 -> 24), both tokens share weight reads ----
  int o = lane & 31, hf = lane >> 5;
  float h0 = 0.f, h1 = 0.f;
  if (o < HID) {
#pragma unroll 4
    for (int ii = 0; ii < 24; ++ii) {
      int i = hf * 24 + ii;
      float bwv = bw1t[i * 25 + o], ssv = ss1t[i * 25 + o];
      float sp0 = 0.f, sp1 = 0.f;
#pragma unroll
      for (int kk = 0; kk < KB; ++kk) {
        float w = sw1t[(i * KB + kk) * 25 + o];
        sp0 += bas1[wave][0][i][kk] * w;
        sp1 += bas1[wave][1][i][kk] * w;
      }
      h0 += sil1[wave][0][i] * bwv + ssv * sp0;
      h1 += sil1[wave][1][i] * bwv + ssv * sp1;
    }
  }
  h0 += __shfl_xor(h0, 32, 64);
  h1 += __shfl_xor(h1, 32, 64);
  if (lane < HID) {
    float hv[2] = {h0, h1};
#pragma unroll
    for (int tt = 0; tt < 2; ++tt) {
      sil2[wave][tt][lane] = hv[tt] / (1.f + __expf(-hv[tt]));
      float bs[KB];
      bspline8(hv[tt], bs);
#pragma unroll
      for (int kk = 0; kk < KB; ++kk) bas2[wave][tt][lane][kk] = bs[kk];
    }
  }
  // ---- phase C: KAN2 (24 -> 48) + residual ----
  if (lane < C) {
    float a0 = 0.f, a1 = 0.f;
#pragma unroll 4
    for (int i = 0; i < HID; ++i) {
      float bwv = bw2t[i * 49 + lane], ssv = ss2t[i * 49 + lane];
      float sp0 = 0.f, sp1 = 0.f;
#pragma unroll
      for (int kk = 0; kk < KB; ++kk) {
        float w = sw2t[(i * KB + kk) * 49 + lane];
        sp0 += bas2[wave][0][i][kk] * w;
        sp1 += bas2[wave][1][i][kk] * w;
      }
      a0 += sil2[wave][0][i] * bwv + ssv * sp0;
      a1 += sil2[wave][1][i] * bwv + ssv * sp1;
    }
    x2[(size_t)tok0 * C + lane] = x1v[0] + a0;
    x2[(size_t)(tok0 + 1) * C + lane] = x1v[1] + a1;
  }
}

// ---------------- kernel 4: conv1 (48 -> 128, k=3) -----------------------
__global__ __launch_bounds__(256) void k_conv1(
    const float* __restrict__ x, const float* __restrict__ w1, const float* __restrict__ bc1,
    float* __restrict__ h1) {
  __shared__ float wt[72 * C1];  // [i3][o] for one i-half
  __shared__ float xr[18 * C];
  int tid = threadIdx.x;
  int b = blockIdx.x >> 6;
  int t0 = (blockIdx.x & 63) << 4;
  for (int e = tid; e < 18 * C; e += 256) {
    int r = e / C, c = e - r * C;
    int n = t0 - 1 + r;
    xr[e] = (n >= 0 && n < N) ? x[(b * N + n) * C + c] : 0.f;
  }
  int wave = tid >> 6, lane = tid & 63;
  int tb = wave << 2;
  float acc0[4] = {0, 0, 0, 0}, acc1[4] = {0, 0, 0, 0};
  for (int hf = 0; hf < 2; ++hf) {
    __syncthreads();
    for (int e = tid; e < 72 * C1; e += 256) {
      int i3 = e >> 7, o = e & 127;
      int ii = i3 / 3, dk = i3 - ii * 3;
      wt[e] = w1[(o * C + hf * 24 + ii) * 3 + dk];
    }
    __syncthreads();
#pragma unroll 4
    for (int ii = 0; ii < 24; ++ii) {
      float xv[6];
#pragma unroll
      for (int j = 0; j < 6; ++j) xv[j] = xr[(tb + j) * C + hf * 24 + ii];
#pragma unroll
      for (int dk = 0; dk < 3; ++dk) {
        float w0 = wt[(ii * 3 + dk) * C1 + lane];
        float w1v = wt[(ii * 3 + dk) * C1 + 64 + lane];
#pragma unroll
        for (int tt = 0; tt < 4; ++tt) {
          float xi = xv[tt + dk];
          acc0[tt] += xi * w0;
          acc1[tt] += xi * w1v;
        }
      }
    }
  }
  float bb0 = bc1[lane], bb1 = bc1[64 + lane];
#pragma unroll
  for (int tt = 0; tt < 4; ++tt) {
    int n = t0 + tb + tt;
    h1[(b * N + n) * C1 + lane] = acc0[tt] + bb0;
    h1[(b * N + n) * C1 + 64 + lane] = acc1[tt] + bb1;
  }
}

// ---------------- kernel 5: conv2 + LN(g1,b1) + sc*h + x2 -> out ---------
__global__ __launch_bounds__(256) void k_conv2out(
    const float* __restrict__ h1, const float* __restrict__ w3, const float* __restrict__ bc3,
    const float* __restrict__ g1, const float* __restrict__ b1,
    const float* __restrict__ x2, const float* __restrict__ scp,
    float* __restrict__ out) {
  __shared__ float wt[192 * C + 16];  // [i3][c] for one i-half (+pad for stray lane reads)
  __shared__ float hr[18 * C1];
  int tid = threadIdx.x;
  int b = blockIdx.x >> 6;
  int t0 = (blockIdx.x & 63) << 4;
  for (int e = tid; e < 18 * C1; e += 256) {
    int r = e >> 7, c = e & 127;
    int n = t0 - 1 + r;
    hr[e] = (n >= 0 && n < N) ? h1[(b * N + n) * C1 + c] : 0.f;
  }
  int wave = tid >> 6, lane = tid & 63;
  int tb = wave << 2;
  float acc[4] = {0, 0, 0, 0};
  for (int hf = 0; hf < 2; ++hf) {
    __syncthreads();
    for (int e = tid; e < 192 * C; e += 256) {
      int i3 = e / C, c = e - i3 * C;
      int ii = i3 / 3, dk = i3 - ii * 3;
      wt[e] = w3[(c * C1 + hf * 64 + ii) * 3 + dk];
    }
    __syncthreads();
#pragma unroll 4
    for (int ii = 0; ii < 64; ++ii) {
      float xv[6];
#pragma unroll
      for (int j = 0; j < 6; ++j) xv[j] = hr[(tb + j) * C1 + hf * 64 + ii];
#pragma unroll
      for (int dk = 0; dk < 3; ++dk) {
        float w = wt[(ii * 3 + dk) * C + lane];
#pragma unroll
        for (int tt = 0; tt < 4; ++tt) acc[tt] += xv[tt + dk] * w;
      }
    }
  }
  float sc0 = scp[0];
#pragma unroll
  for (int tt = 0; tt < 4; ++tt) {
    int n = t0 + tb + tt;
    float val = (lane < C) ? acc[tt] + bc3[lane] : 0.f;
    float s = wsum(val), s2 = wsum(val * val);
    float mean = s * (1.f / C), var = s2 * (1.f / C) - mean * mean;
    float rstd = rsqrtf(var + 1e-5f);
    if (lane < C) {
      float hn = (val - mean) * rstd * g1[lane] + b1[lane];
      out[(b * N + n) * C + lane] = sc0 * hn + x2[(size_t)(b * N + n) * C + lane];
    }
  }
}

extern "C" void kernel_launch(void* const* d_in, const int* in_sizes, int n_in,
                              void* d_out, int out_size, void* d_ws, size_t ws_size,
                              hipStream_t stream) {
  (void)in_sizes; (void)n_in; (void)out_size; (void)ws_size;
  const float* x    = (const float*)d_in[0];
  const float* g1   = (const float*)d_in[1];
  const float* b1   = (const float*)d_in[2];
  const float* wqkv = (const float*)d_in[3];
  const float* wp   = (const float*)d_in[4];
  const float* bp   = (const float*)d_in[5];
  const float* g2   = (const float*)d_in[6];
  const float* b2   = (const float*)d_in[7];
  const float* bw1  = (const float*)d_in[8];
  const float* sw1  = (const float*)d_in[9];
  const float* ss1  = (const float*)d_in[10];
  const float* bw2  = (const float*)d_in[11];
  const float* sw2  = (const float*)d_in[12];
  const float* ss2  = (const float*)d_in[13];
  const float* w1   = (const float*)d_in[14];
  const float* bc1  = (const float*)d_in[15];
  const float* w3   = (const float*)d_in[16];
  const float* bc3  = (const float*)d_in[17];
  const float* scp  = (const float*)d_in[18];

  float* out  = (float*)d_out;
  float* attn = out + (size_t)NT * C;  // out first, then attn_global

  float* ws   = (float*)d_ws;
  float* q    = ws;                 // 393216
  float* k    = ws + 393216;
  float* v    = ws + 786432;
  float* xgl  = ws + 1179648;       // global+local attn output (B,N,C)
  float* x2   = ws + 1572864;
  float* h1   = ws + 1966080;       // (B,N,128) = 1048576

  k_ln_qkv<<<NT / 4, 256, 0, stream>>>(x, g1, b1, wqkv, q, k, v);
  k_gattn<<<B * H * 16, 256, 0, stream>>>(q, k, v, attn, xgl);
  k_mlp<<<NT / 16, 512, 0, stream>>>(x, xgl, wp, bp, g2, b2,
                                     bw1, sw1, ss1, bw2, sw2, ss2, x2);
  k_conv1<<<512, 256, 0, stream>>>(x, w1, bc1, h1);
  k_conv2out<<<512, 256, 0, stream>>>(h1, w3, bc3, g1, b1, x2, scp, out);
}